// Round 9
// baseline (333.070 us; speedup 1.0000x reference)
//
#include <hip/hip_runtime.h>

// ---------- types ----------
typedef __attribute__((ext_vector_type(8))) __bf16 bf16x8;
typedef __attribute__((ext_vector_type(4))) __bf16 bf16x4;
typedef __attribute__((ext_vector_type(4))) float f32x4;
typedef __attribute__((ext_vector_type(8))) unsigned short u16x8;

// native casts -> v_cvt_pk_bf16_f32 (RNE) on gfx950
__device__ __forceinline__ bf16x8 cvt8(float4 a, float4 b) {
    bf16x8 o;
    o[0] = (__bf16)a.x; o[1] = (__bf16)a.y; o[2] = (__bf16)a.z; o[3] = (__bf16)a.w;
    o[4] = (__bf16)b.x; o[5] = (__bf16)b.y; o[6] = (__bf16)b.z; o[7] = (__bf16)b.w;
    return o;
}
__device__ __forceinline__ bf16x4 cvt4(f32x4 v) {
    bf16x4 o;
    o[0] = (__bf16)v[0]; o[1] = (__bf16)v[1]; o[2] = (__bf16)v[2]; o[3] = (__bf16)v[3];
    return o;
}

// m201 st_16x32 swizzle on 64B rows: flips byte-bit5 with row-bit3.
__device__ __forceinline__ unsigned swz(int row, int s) {
    return (unsigned)((row * 64 + s * 16) ^ ((row & 8) << 2));
}

// ---------- W [K][N=512] f32 -> pre-tiled + pre-swizzled bf16 image ----------
// tile (cb, tt): cols cb*256..+255 x K tt*32..+31; byte = swz(n&255,(k&31)>>3)+(k&7)*2
__global__ __launch_bounds__(256) void convw_pre_kernel(const float* __restrict__ W,
                                                        char* __restrict__ out, int K) {
    int t = blockIdx.x * 256 + threadIdx.x;
    if (t >= K * 512) return;
    int k = t >> 9, n = t & 511;
    int cb = n >> 8, r = n & 255, tt = k >> 5, s = (k & 31) >> 3, e = k & 7;
    size_t off = ((size_t)cb * (K >> 5) + tt) * 16384 + swz(r, s) + e * 2;
    *(__bf16*)(out + off) = (__bf16)W[t];
}

// ---------- CSR build (by dst) ----------
__global__ __launch_bounds__(256) void count_kernel(const int* __restrict__ dst,
                                                    int* __restrict__ counts, int E) {
    int e = blockIdx.x * 256 + threadIdx.x;
    if (e < E) atomicAdd(&counts[dst[e]], 1);
}

__global__ __launch_bounds__(1024) void scan_kernel(const int* __restrict__ counts,
                                                    int* __restrict__ offs, int N) {
    __shared__ int wsum[16], wpre[16];
    const int CH = 20;
    int tid = threadIdx.x, lane = tid & 63, wv = tid >> 6;
    int base = tid * CH;
    int s = 0;
    for (int i = 0; i < CH; i++) { int idx = base + i; s += (idx < N) ? counts[idx] : 0; }
    int run = s;
#pragma unroll
    for (int o = 1; o < 64; o <<= 1) { int v = __shfl_up(run, o, 64); if (lane >= o) run += v; }
    if (lane == 63) wsum[wv] = run;
    __syncthreads();
    if (tid == 0) { int acc = 0; for (int w = 0; w < 16; w++) { wpre[w] = acc; acc += wsum[w]; } }
    __syncthreads();
    int pre = wpre[wv] + (run - s);
    for (int i = 0; i < CH; i++) {
        int idx = base + i;
        if (idx <= N) offs[idx] = pre;
        pre += (idx < N) ? counts[idx] : 0;
    }
}

__global__ __launch_bounds__(256) void bucket_kernel(const int* __restrict__ src,
                                                     const int* __restrict__ dst,
                                                     const int* __restrict__ offs,
                                                     int* __restrict__ cursor,
                                                     int* __restrict__ eids, int E) {
    int e = blockIdx.x * 256 + threadIdx.x;
    if (e >= E) return;
    int d = dst[e];
    int pos = atomicAdd(&cursor[d], 1);
    eids[offs[d] + pos] = src[e];
}

// ---------- gather + h1: h1 = bf16(relu(y[i] + sum_j y[nbr] + b1)) ----------
__global__ __launch_bounds__(256) void gather_h1_kernel(const float* __restrict__ y,
                                                        const int* __restrict__ offs,
                                                        const int* __restrict__ eids,
                                                        const float* __restrict__ b1,
                                                        __bf16* __restrict__ h1b,
                                                        int N) {
    int node = blockIdx.x * 2 + (threadIdx.x >> 7);
    if (node >= N) return;
    int c = (threadIdx.x & 127) << 2;
    float4 s = *(const float4*)(y + (size_t)node * 512 + c);
    int beg = offs[node], end = offs[node + 1];
    for (int k = beg; k < end; k++) {
        int sn = eids[k];
        const float4 v = *(const float4*)(y + (size_t)sn * 512 + c);
        s.x += v.x; s.y += v.y; s.z += v.z; s.w += v.w;
    }
    const float4 b = *(const float4*)(b1 + c);
    f32x4 r;
    r[0] = fmaxf(s.x + b.x, 0.f);
    r[1] = fmaxf(s.y + b.y, 0.f);
    r[2] = fmaxf(s.z + b.z, 0.f);
    r[3] = fmaxf(s.w + b.w, 0.f);
    *(bf16x4*)(h1b + (size_t)node * 512 + c) = cvt4(r);
}

// =====================================================================
// GEMM1: Y[M][512] = X[M][2048](f32) @ W1 — no B staging, reg prefetch.
// 256 thr (4 waves), BM=64, BN=256 (cb=blockIdx.y), A-tile BK=64.
// A: depth-2 register prefetch (A(t+1),A(t+2) in regs) -> ds_write gets
//    ~2 compute phases of HBM-latency cover. B: wf tile prefetched 1 ahead
//    from pre-tiled L2-resident image. Barriers: lgkmcnt(0)+s_barrier only.
// Swapped MFMA: D = Wfrag*Afrag; node=lane&15, weightcol=(lane>>4)*4+r.
// =====================================================================
__global__ __launch_bounds__(256) void gemm1_kernel(const float* __restrict__ X,
                                                    const char* __restrict__ Bpre,
                                                    float* __restrict__ Y, int M) {
    constexpr int KDIM = 2048, NT2 = KDIM / 64;   // 32 outer iters, 64 k-tiles
    __shared__ char smem[16384];
    const int tid = threadIdx.x, lane = tid & 63, wv = tid >> 6;
    const int fr = lane & 15, sec = lane >> 4, hi4 = (lane >> 4) * 4;
    const long row0 = (long)blockIdx.x * 64;
    const char* Bp = Bpre + (size_t)blockIdx.y * 64 * 16384;

    f32x4 acc[4][4];
#pragma unroll
    for (int m = 0; m < 4; m++)
#pragma unroll
        for (int n = 0; n < 4; n++)
#pragma unroll
            for (int r = 0; r < 4; r++) acc[m][n][r] = 0.f;

    const int ar_ = tid >> 2, ks = tid & 3;
    const unsigned awz = swz(ar_, ks);
    long arow = row0 + ar_; if (arow > (long)M - 1) arow = M - 1;
    const float* Ap = X + arow * KDIM;

#define ASEC(b) (smem + (b) * 8192)
#define LOAD_A(d0, d1, d2, d3, t) do {                       \
        const float* p_ = Ap + (t) * 64 + ks * 8;            \
        d0 = *(const float4*)(p_);                           \
        d1 = *(const float4*)(p_ + 4);                       \
        d2 = *(const float4*)(p_ + 32);                      \
        d3 = *(const float4*)(p_ + 36);                      \
    } while (0)
#define LOAD_WF(dst, g) do {                                              \
        const char* bt_ = Bp + (size_t)(g) * 16384;                       \
        _Pragma("unroll") for (int m_ = 0; m_ < 4; m_++)                  \
            dst[m_] = *(const bf16x8*)(bt_ + swz(wv * 64 + m_ * 16 + fr, sec)); \
    } while (0)

    float4 aP0, aP1, aP2, aP3, aN0, aN1, aN2, aN3;
    bf16x8 wfC[4], wfN[4];

    // prologue: A(0)->LDS0; A(1)->aP; A(2)->aN; wf tile0
    LOAD_A(aP0, aP1, aP2, aP3, 0);
    *(bf16x8*)(ASEC(0) + awz) = cvt8(aP0, aP1);
    *(bf16x8*)(ASEC(0) + 4096 + awz) = cvt8(aP2, aP3);
    LOAD_A(aP0, aP1, aP2, aP3, 1);
    LOAD_A(aN0, aN1, aN2, aN3, 2);
    LOAD_WF(wfC, 0);
    asm volatile("s_waitcnt lgkmcnt(0)" ::: "memory");
    __builtin_amdgcn_s_barrier();

    int cur = 0;
    for (int tt = 0; tt < NT2; tt++) {
#pragma unroll
        for (int h = 0; h < 2; h++) {
            const int g = tt * 2 + h;
            if (g + 1 < NT2 * 2) LOAD_WF(wfN, g + 1);
            bf16x8 xf[4];
#pragma unroll
            for (int n = 0; n < 4; n++)
                xf[n] = *(const bf16x8*)(ASEC(cur) + h * 4096 + swz(n * 16 + fr, sec));
#pragma unroll
            for (int m = 0; m < 4; m++)
#pragma unroll
                for (int n = 0; n < 4; n++)
                    acc[m][n] = __builtin_amdgcn_mfma_f32_16x16x32_bf16(wfC[m], xf[n], acc[m][n], 0, 0, 0);
#pragma unroll
            for (int m = 0; m < 4; m++) wfC[m] = wfN[m];
        }
        if (tt + 1 < NT2) {
            const int nxt = cur ^ 1;
            *(bf16x8*)(ASEC(nxt) + awz) = cvt8(aP0, aP1);
            *(bf16x8*)(ASEC(nxt) + 4096 + awz) = cvt8(aP2, aP3);
            aP0 = aN0; aP1 = aN1; aP2 = aN2; aP3 = aN3;
            if (tt + 3 < NT2) LOAD_A(aN0, aN1, aN2, aN3, tt + 3);
            asm volatile("s_waitcnt lgkmcnt(0)" ::: "memory");
            __builtin_amdgcn_s_barrier();
            cur = nxt;
        }
    }
#undef ASEC
#undef LOAD_A
#undef LOAD_WF

#pragma unroll
    for (int n = 0; n < 4; n++) {
        long node = row0 + n * 16 + fr;
        if (node < M) {
#pragma unroll
            for (int m = 0; m < 4; m++)
                *(f32x4*)(Y + node * 512 + blockIdx.y * 256 + wv * 64 + m * 16 + hi4) = acc[m][n];
        }
    }
}

// =====================================================================
// Fused MLP2+gate: h = h1@W2+b2 -> hout (f32) AND h-tile in LDS (bf16,
// pre-tiled swizzled); then alpha[node] = sum_gc tanh(h@Wg+bg)[gc]*Wa[gc]
// straight from LDS (phase 2 barrier-free).
// 512 thr (8 waves), BM=32 nodes, BN=512 (all cols). Grid 625 (20000/32).
// LDS 41216B: A dbuf 2x4KB @0, Hs 16 tiles x 2KB @8192, aS[32] @40960.
// =====================================================================
__global__ __launch_bounds__(512) void mlp23_kernel(const __bf16* __restrict__ H1,
                                                    const char* __restrict__ W2p,
                                                    const float* __restrict__ b2,
                                                    const char* __restrict__ Wgp,
                                                    const float* __restrict__ bg,
                                                    const float* __restrict__ Wa,
                                                    float* __restrict__ Hout,
                                                    float* __restrict__ alpha) {
    constexpr int NT2 = 8;    // K=512 -> 8 outer iters (BK=64), 16 k-tiles
    __shared__ char smem[41216];
    char* Hs = smem + 8192;
    float* aS = (float*)(smem + 40960);
    const int tid = threadIdx.x, lane = tid & 63, wv = tid >> 6;
    const int fr = lane & 15, sec = lane >> 4, hi4 = (lane >> 4) * 4;
    const long row0 = (long)blockIdx.x * 32;
    const int cbv = wv >> 2, rbase = (wv & 3) * 64;   // weight image coords

    if (tid < 32) aS[tid] = 0.f;

    // A staging: tid<256: row=tid>>3 (32 rows), piece p=tid&7 -> h=p>>2, s=p&3
    const int srow = tid >> 3, sh = (tid & 7) >> 2, ss = tid & 3;
    const unsigned awz = (unsigned)(sh * 2048) + swz(srow, ss);
    const __bf16* ApH = H1 + (row0 + srow) * 512 + sh * 32 + ss * 8;

#define ASEC(b) (smem + (b) * 4096)
#define LOAD_WF(dst, img, g) do {                                         \
        const char* bt_ = (img) + ((size_t)cbv * 16 + (g)) * 16384;       \
        _Pragma("unroll") for (int m_ = 0; m_ < 4; m_++)                  \
            dst[m_] = *(const bf16x8*)(bt_ + swz(rbase + m_ * 16 + fr, sec)); \
    } while (0)

    f32x4 acc[4][2];
#pragma unroll
    for (int m = 0; m < 4; m++)
#pragma unroll
        for (int n = 0; n < 2; n++)
#pragma unroll
            for (int r = 0; r < 4; r++) acc[m][n][r] = 0.f;

    bf16x8 wfC[4], wfN[4];
    // prologue
    if (tid < 256) {
        u16x8 v = *(const u16x8*)(ApH);
        *(u16x8*)(ASEC(0) + awz) = v;
    }
    LOAD_WF(wfC, W2p, 0);
    asm volatile("s_waitcnt lgkmcnt(0)" ::: "memory");
    __builtin_amdgcn_s_barrier();

    // ---- phase 1: h = h1 @ W2 ----
    int cur = 0;
    for (int tt = 0; tt < NT2; tt++) {
        u16x8 av;
        const bool more = (tt + 1 < NT2);
        if (more && tid < 256) av = *(const u16x8*)(ApH + (tt + 1) * 64);
#pragma unroll
        for (int h = 0; h < 2; h++) {
            const int g = tt * 2 + h;
            if (g + 1 < 16) LOAD_WF(wfN, W2p, g + 1);
            bf16x8 xf[2];
#pragma unroll
            for (int n = 0; n < 2; n++)
                xf[n] = *(const bf16x8*)(ASEC(cur) + h * 2048 + swz(n * 16 + fr, sec));
#pragma unroll
            for (int m = 0; m < 4; m++)
#pragma unroll
                for (int n = 0; n < 2; n++)
                    acc[m][n] = __builtin_amdgcn_mfma_f32_16x16x32_bf16(wfC[m], xf[n], acc[m][n], 0, 0, 0);
#pragma unroll
            for (int m = 0; m < 4; m++) wfC[m] = wfN[m];
        }
        if (more) {
            const int nxt = cur ^ 1;
            if (tid < 256) *(u16x8*)(ASEC(nxt) + awz) = av;
            asm volatile("s_waitcnt lgkmcnt(0)" ::: "memory");
            __builtin_amdgcn_s_barrier();
            cur = nxt;
        }
    }

    // phase-1 epilogue: hout f32 + Hs bf16 (pre-tiled swizzled image)
#pragma unroll
    for (int n = 0; n < 2; n++) {
        int node = n * 16 + fr;
        long gnode = row0 + node;
#pragma unroll
        for (int m = 0; m < 4; m++) {
            int hc = wv * 64 + m * 16 + hi4;
            f32x4 bv = *(const f32x4*)(b2 + hc);
            f32x4 v = acc[m][n] + bv;
            *(f32x4*)(Hout + gnode * 512 + hc) = v;
            int tt = hc >> 5, sk = (hc & 31) >> 3, e = hc & 7;
            *(bf16x4*)(Hs + tt * 2048 + swz(node, sk) + e * 2) = cvt4(v);
        }
    }
    asm volatile("s_waitcnt lgkmcnt(0)" ::: "memory");
    __builtin_amdgcn_s_barrier();

    // ---- phase 2: gate (barrier-free; Hs complete) ----
    f32x4 acc2[4][2];
#pragma unroll
    for (int m = 0; m < 4; m++)
#pragma unroll
        for (int n = 0; n < 2; n++)
#pragma unroll
            for (int r = 0; r < 4; r++) acc2[m][n][r] = 0.f;

    LOAD_WF(wfC, Wgp, 0);
    for (int g = 0; g < 16; g++) {
        if (g + 1 < 16) LOAD_WF(wfN, Wgp, g + 1);
        bf16x8 xf[2];
#pragma unroll
        for (int n = 0; n < 2; n++)
            xf[n] = *(const bf16x8*)(Hs + g * 2048 + swz(n * 16 + fr, sec));
#pragma unroll
        for (int m = 0; m < 4; m++)
#pragma unroll
            for (int n = 0; n < 2; n++)
                acc2[m][n] = __builtin_amdgcn_mfma_f32_16x16x32_bf16(wfC[m], xf[n], acc2[m][n], 0, 0, 0);
#pragma unroll
        for (int m = 0; m < 4; m++) wfC[m] = wfN[m];
    }
#undef ASEC
#undef LOAD_WF

    // epilogue 2: tanh + Wa dot, reduce over gate cols
#pragma unroll
    for (int n = 0; n < 2; n++) {
        float s = 0.f;
#pragma unroll
        for (int m = 0; m < 4; m++) {
            int gc = wv * 64 + m * 16 + hi4;
            f32x4 bgv = *(const f32x4*)(bg + gc);
            f32x4 wav = *(const f32x4*)(Wa + gc);
#pragma unroll
            for (int r = 0; r < 4; r++)
                s += tanhf(acc2[m][n][r] + bgv[r]) * wav[r];
        }
        s += __shfl_xor(s, 16, 64);
        s += __shfl_xor(s, 32, 64);
        if (sec == 0) atomicAdd(&aS[n * 16 + fr], s);
    }
    __syncthreads();
    if (tid < 32) alpha[row0 + tid] = aS[tid];
}

// ---------- softmax over 20000 scalars (ba cancels) ----------
__global__ __launch_bounds__(1024) void softmax_kernel(const float* __restrict__ alpha,
                                                       float* __restrict__ att, int N) {
    __shared__ float red[16];
    __shared__ float bc[2];
    int tid = threadIdx.x, lane = tid & 63, wv = tid >> 6;
    float m = -3.4e38f;
    for (int i = tid; i < N; i += 1024) m = fmaxf(m, alpha[i]);
#pragma unroll
    for (int o = 32; o > 0; o >>= 1) m = fmaxf(m, __shfl_xor(m, o, 64));
    if (lane == 0) red[wv] = m;
    __syncthreads();
    if (tid == 0) {
        float mm = red[0];
        for (int i = 1; i < 16; i++) mm = fmaxf(mm, red[i]);
        bc[0] = mm;
    }
    __syncthreads();
    float Mx = bc[0];
    float s = 0.f;
    for (int i = tid; i < N; i += 1024) s += expf(alpha[i] - Mx);
#pragma unroll
    for (int o = 32; o > 0; o >>= 1) s += __shfl_xor(s, o, 64);
    if (lane == 0) red[wv] = s;
    __syncthreads();
    if (tid == 0) {
        float ss = 0.f;
        for (int i = 0; i < 16; i++) ss += red[i];
        bc[1] = ss;
    }
    __syncthreads();
    float inv = 1.f / bc[1];
    for (int i = tid; i < N; i += 1024) att[i] = expf(alpha[i] - Mx) * inv;
}

// ---------- launch ----------
extern "C" void kernel_launch(void* const* d_in, const int* in_sizes, int n_in,
                              void* d_out, int out_size, void* d_ws, size_t ws_size,
                              hipStream_t stream) {
    const float* x  = (const float*)d_in[0];
    const int*   ei = (const int*)d_in[1];     // [2][160000]: src then dst
    const float* W1 = (const float*)d_in[2];
    const float* b1 = (const float*)d_in[3];
    const float* W2 = (const float*)d_in[4];
    const float* b2 = (const float*)d_in[5];
    const float* Wg = (const float*)d_in[6];
    const float* bg = (const float*)d_in[7];
    const float* Wa = (const float*)d_in[8];
    // d_in[9] = ba: cancels in softmax, unused.

    const int M = 20000, IN = 2048, H = 512, E = 160000;

    char* ws = (char*)d_ws;
    float* y      = (float*)ws;                 // 40,960,000
    char*  W1p    = ws + 40960000;              //  2,097,152
    char*  W2p    = ws + 43057152;              //    524,288
    char*  Wgp    = ws + 43581440;              //    524,288
    __bf16* h1b   = (__bf16*)(ws + 44105728);   // 20,480,000
    float* alpha  = (float*)(ws + 64585728);    //     80,000
    int*   counts = (int*)(ws + 64665728);      //     80,000
    int*   offs   = (int*)(ws + 64745728);      //     80,004
    int*   cursor = (int*)(ws + 64825732);      //     80,000
    int*   eids   = (int*)(ws + 64905732);      //    640,000

    float* hout = (float*)d_out;                 // [20000][512] f32
    float* att  = hout + (size_t)M * H;          // [20000] f32

    // weights -> pre-tiled + pre-swizzled images (bf16)
    convw_pre_kernel<<<4096, 256, 0, stream>>>(W1, W1p, IN);
    convw_pre_kernel<<<1024, 256, 0, stream>>>(W2, W2p, H);
    convw_pre_kernel<<<1024, 256, 0, stream>>>(Wg, Wgp, H);

    // CSR build by dst
    hipMemsetAsync(counts, 0, M * 4, stream);
    count_kernel<<<(E + 255) / 256, 256, 0, stream>>>(ei + E, counts, E);
    scan_kernel<<<1, 1024, 0, stream>>>(counts, offs, M);
    hipMemsetAsync(cursor, 0, M * 4, stream);
    bucket_kernel<<<(E + 255) / 256, 256, 0, stream>>>(ei, ei + E, offs, cursor, eids, E);

    // y = x @ W1  (reg-prefetched, no B staging)
    gemm1_kernel<<<dim3(313, 2), 256, 0, stream>>>(x, W1p, y, M);

    // h1 = bf16(relu(y_self + gather(y) + b1))
    gather_h1_kernel<<<10000, 256, 0, stream>>>(y, offs, eids, b1, h1b, M);

    // h = h1@W2+b2 -> d_out, fused alpha = rowsum(tanh(h@Wg+bg)*Wa)
    mlp23_kernel<<<625, 512, 0, stream>>>(h1b, W2p, b2, Wgp, bg, Wa, hout, alpha);

    // att = softmax(alpha)
    softmax_kernel<<<1, 1024, 0, stream>>>(alpha, att, M);
}

// Round 10
// 318.187 us; speedup vs baseline: 1.0468x; 1.0468x over previous
//
#include <hip/hip_runtime.h>

// ---------- types ----------
typedef __attribute__((ext_vector_type(8))) __bf16 bf16x8;
typedef __attribute__((ext_vector_type(4))) __bf16 bf16x4;
typedef __attribute__((ext_vector_type(4))) float f32x4;
typedef __attribute__((ext_vector_type(8))) unsigned short u16x8;

// native casts -> v_cvt_pk_bf16_f32 (RNE) on gfx950
__device__ __forceinline__ bf16x8 cvt8(float4 a, float4 b) {
    bf16x8 o;
    o[0] = (__bf16)a.x; o[1] = (__bf16)a.y; o[2] = (__bf16)a.z; o[3] = (__bf16)a.w;
    o[4] = (__bf16)b.x; o[5] = (__bf16)b.y; o[6] = (__bf16)b.z; o[7] = (__bf16)b.w;
    return o;
}
__device__ __forceinline__ bf16x4 cvt4(f32x4 v) {
    bf16x4 o;
    o[0] = (__bf16)v[0]; o[1] = (__bf16)v[1]; o[2] = (__bf16)v[2]; o[3] = (__bf16)v[3];
    return o;
}

// m201 st_16x32 swizzle on 64B rows: flips byte-bit5 with row-bit3.
__device__ __forceinline__ unsigned swz(int row, int s) {
    return (unsigned)((row * 64 + s * 16) ^ ((row & 8) << 2));
}

// ---------- W [K][N=512] f32 -> pre-tiled + pre-swizzled bf16 image ----------
// tile (cb, tt): cols cb*256..+255 x K tt*32..+31; byte = swz(n&255,(k&31)>>3)+(k&7)*2
__global__ __launch_bounds__(256) void convw_pre_kernel(const float* __restrict__ W,
                                                        char* __restrict__ out, int K) {
    int t = blockIdx.x * 256 + threadIdx.x;
    if (t >= K * 512) return;
    int k = t >> 9, n = t & 511;
    int cb = n >> 8, r = n & 255, tt = k >> 5, s = (k & 31) >> 3, e = k & 7;
    size_t off = ((size_t)cb * (K >> 5) + tt) * 16384 + swz(r, s) + e * 2;
    *(__bf16*)(out + off) = (__bf16)W[t];
}

// ---------- CSR build (by dst) ----------
__global__ __launch_bounds__(256) void count_kernel(const int* __restrict__ dst,
                                                    int* __restrict__ counts, int E) {
    int e = blockIdx.x * 256 + threadIdx.x;
    if (e < E) atomicAdd(&counts[dst[e]], 1);
}

__global__ __launch_bounds__(1024) void scan_kernel(const int* __restrict__ counts,
                                                    int* __restrict__ offs, int N) {
    __shared__ int wsum[16], wpre[16];
    const int CH = 20;
    int tid = threadIdx.x, lane = tid & 63, wv = tid >> 6;
    int base = tid * CH;
    int s = 0;
    for (int i = 0; i < CH; i++) { int idx = base + i; s += (idx < N) ? counts[idx] : 0; }
    int run = s;
#pragma unroll
    for (int o = 1; o < 64; o <<= 1) { int v = __shfl_up(run, o, 64); if (lane >= o) run += v; }
    if (lane == 63) wsum[wv] = run;
    __syncthreads();
    if (tid == 0) { int acc = 0; for (int w = 0; w < 16; w++) { wpre[w] = acc; acc += wsum[w]; } }
    __syncthreads();
    int pre = wpre[wv] + (run - s);
    for (int i = 0; i < CH; i++) {
        int idx = base + i;
        if (idx <= N) offs[idx] = pre;
        pre += (idx < N) ? counts[idx] : 0;
    }
}

__global__ __launch_bounds__(256) void bucket_kernel(const int* __restrict__ src,
                                                     const int* __restrict__ dst,
                                                     const int* __restrict__ offs,
                                                     int* __restrict__ cursor,
                                                     int* __restrict__ eids, int E) {
    int e = blockIdx.x * 256 + threadIdx.x;
    if (e >= E) return;
    int d = dst[e];
    int pos = atomicAdd(&cursor[d], 1);
    eids[offs[d] + pos] = src[e];
}

// ---------- gather + h1 (y is bf16): one wave per node, 16B/lane ----------
__global__ __launch_bounds__(256) void gather_h1_kernel(const __bf16* __restrict__ y,
                                                        const int* __restrict__ offs,
                                                        const int* __restrict__ eids,
                                                        const float* __restrict__ b1,
                                                        __bf16* __restrict__ h1b) {
    const int node = blockIdx.x * 4 + (threadIdx.x >> 6);
    const int c = (threadIdx.x & 63) * 8;
    float s[8];
    bf16x8 v = *(const bf16x8*)(y + (size_t)node * 512 + c);
#pragma unroll
    for (int j = 0; j < 8; j++) s[j] = (float)v[j];
    const int beg = offs[node], end = offs[node + 1];   // wave-uniform
    for (int k = beg; k < end; k++) {
        int sn = eids[k];
        bf16x8 u = *(const bf16x8*)(y + (size_t)sn * 512 + c);
#pragma unroll
        for (int j = 0; j < 8; j++) s[j] += (float)u[j];
    }
    bf16x8 o;
#pragma unroll
    for (int j = 0; j < 8; j++) o[j] = (__bf16)fmaxf(s[j] + b1[c + j], 0.f);
    *(bf16x8*)(h1b + (size_t)node * 512 + c) = o;
}

// =====================================================================
// GEMM1: Y[20000][512](bf16) = X[20000][2048](f32) @ W1
// 256 thr (4 waves), BM=32 (grid.x=625 EXACT, no tail), BN=256 (grid.y=2).
// A: f32->bf16 cvt in staging, LDS dbuf 2x4KB, st_16x32 swizzle.
// B: direct from pre-tiled L2-resident image (no staging).
// Barriers: lgkmcnt(0) + raw s_barrier only (no vmcnt drain).
// Swapped MFMA: D = Wfrag*Afrag; node=lane&15, weightcol=(lane>>4)*4+r.
// =====================================================================
__global__ __launch_bounds__(256) void gemm1_kernel(const float* __restrict__ X,
                                                    const char* __restrict__ Bpre,
                                                    __bf16* __restrict__ Y) {
    constexpr int KDIM = 2048, NT2 = KDIM / 64;   // 32 iters, 64 k-tiles
    __shared__ char smem[8192];
    const int tid = threadIdx.x, lane = tid & 63, wv = tid >> 6;
    const int fr = lane & 15, sec = lane >> 4, hi4 = (lane >> 4) * 4;
    const int row0 = blockIdx.x * 32;
    const char* Bp = Bpre + (size_t)blockIdx.y * 64 * 16384;

    f32x4 acc[4][2];
#pragma unroll
    for (int m = 0; m < 4; m++)
#pragma unroll
        for (int n = 0; n < 2; n++)
#pragma unroll
            for (int r = 0; r < 4; r++) acc[m][n][r] = 0.f;

    // A staging: row r_=tid>>3 (32 rows), piece p=tid&7 -> half h_, sector s_
    const int r_ = tid >> 3, h_ = (tid & 7) >> 2, s_ = tid & 3;
    const unsigned awz = (unsigned)(h_ * 2048) + swz(r_, s_);
    const float* Ap = X + (size_t)(row0 + r_) * KDIM + h_ * 32 + s_ * 8;

#define ASEC(b) (smem + (b) * 4096)

    {   // prologue
        float4 a0 = *(const float4*)(Ap), a1 = *(const float4*)(Ap + 4);
        *(bf16x8*)(ASEC(0) + awz) = cvt8(a0, a1);
    }
    asm volatile("s_waitcnt lgkmcnt(0)" ::: "memory");
    __builtin_amdgcn_s_barrier();

    int cur = 0;
    for (int tt = 0; tt < NT2; tt++) {
        const bool more = (tt + 1 < NT2);
        float4 a0, a1;
        if (more) {   // issue next A loads early
            a0 = *(const float4*)(Ap + (tt + 1) * 64);
            a1 = *(const float4*)(Ap + (tt + 1) * 64 + 4);
        }
#pragma unroll
        for (int h = 0; h < 2; h++) {
            const char* bt = Bp + (size_t)(tt * 2 + h) * 16384;
            bf16x8 wf[4], xf[2];
#pragma unroll
            for (int m = 0; m < 4; m++)
                wf[m] = *(const bf16x8*)(bt + swz(wv * 64 + m * 16 + fr, sec));  // L2
#pragma unroll
            for (int n = 0; n < 2; n++)
                xf[n] = *(const bf16x8*)(ASEC(cur) + h * 2048 + swz(n * 16 + fr, sec));
#pragma unroll
            for (int m = 0; m < 4; m++)
#pragma unroll
                for (int n = 0; n < 2; n++)
                    acc[m][n] = __builtin_amdgcn_mfma_f32_16x16x32_bf16(wf[m], xf[n], acc[m][n], 0, 0, 0);
        }
        if (more) {
            const int nxt = cur ^ 1;
            *(bf16x8*)(ASEC(nxt) + awz) = cvt8(a0, a1);
            asm volatile("s_waitcnt lgkmcnt(0)" ::: "memory");
            __builtin_amdgcn_s_barrier();
            cur = nxt;
        }
    }
#undef ASEC

    // epilogue: y bf16 store
#pragma unroll
    for (int n = 0; n < 2; n++) {
        int node = row0 + n * 16 + fr;
#pragma unroll
        for (int m = 0; m < 4; m++) {
            int col = blockIdx.y * 256 + wv * 64 + m * 16 + hi4;
            *(bf16x4*)(Y + (size_t)node * 512 + col) = cvt4(acc[m][n]);
        }
    }
}

// =====================================================================
// Fused MLP2+gate: h = h1@W2+b2 -> hout (f32) AND h-tile in LDS (bf16,
// pre-tiled swizzled); then alpha[node] = sum_gc tanh(h@Wg+bg)[gc]*Wa[gc].
// 512 thr (8 waves), BM=32 nodes, BN=512. Grid 625 (exact).
// LDS 41216B: A dbuf 2x4KB @0, Hs 16x2KB @8192, aS[32] @40960.
// =====================================================================
__global__ __launch_bounds__(512) void mlp23_kernel(const __bf16* __restrict__ H1,
                                                    const char* __restrict__ W2p,
                                                    const float* __restrict__ b2,
                                                    const char* __restrict__ Wgp,
                                                    const float* __restrict__ bg,
                                                    const float* __restrict__ Wa,
                                                    float* __restrict__ Hout,
                                                    float* __restrict__ alpha) {
    constexpr int NT2 = 8;    // K=512 -> 8 iters (BK=64), 16 k-tiles
    __shared__ char smem[41216];
    char* Hs = smem + 8192;
    float* aS = (float*)(smem + 40960);
    const int tid = threadIdx.x, lane = tid & 63, wv = tid >> 6;
    const int fr = lane & 15, sec = lane >> 4, hi4 = (lane >> 4) * 4;
    const long row0 = (long)blockIdx.x * 32;
    const int cbv = wv >> 2, rbase = (wv & 3) * 64;   // weight image coords

    if (tid < 32) aS[tid] = 0.f;

    // A staging (tid<256): row=tid>>3, piece p=tid&7 -> half, sector
    const int srow = tid >> 3, sh = (tid & 7) >> 2, ss = tid & 3;
    const unsigned awz = (unsigned)(sh * 2048) + swz(srow, ss);
    const __bf16* ApH = H1 + (row0 + srow) * 512 + sh * 32 + ss * 8;

#define ASEC(b) (smem + (b) * 4096)

    f32x4 acc[4][2];
#pragma unroll
    for (int m = 0; m < 4; m++)
#pragma unroll
        for (int n = 0; n < 2; n++)
#pragma unroll
            for (int r = 0; r < 4; r++) acc[m][n][r] = 0.f;

    // prologue
    if (tid < 256) {
        u16x8 v = *(const u16x8*)(ApH);
        *(u16x8*)(ASEC(0) + awz) = v;
    }
    asm volatile("s_waitcnt lgkmcnt(0)" ::: "memory");
    __builtin_amdgcn_s_barrier();

    // ---- phase 1: h = h1 @ W2 ----
    int cur = 0;
    for (int tt = 0; tt < NT2; tt++) {
        u16x8 av;
        const bool more = (tt + 1 < NT2);
        if (more && tid < 256) av = *(const u16x8*)(ApH + (tt + 1) * 64);
#pragma unroll
        for (int h = 0; h < 2; h++) {
            const char* bt = W2p + ((size_t)cbv * 16 + tt * 2 + h) * 16384;
            bf16x8 wf[4], xf[2];
#pragma unroll
            for (int m = 0; m < 4; m++)
                wf[m] = *(const bf16x8*)(bt + swz(rbase + m * 16 + fr, sec));
#pragma unroll
            for (int n = 0; n < 2; n++)
                xf[n] = *(const bf16x8*)(ASEC(cur) + h * 2048 + swz(n * 16 + fr, sec));
#pragma unroll
            for (int m = 0; m < 4; m++)
#pragma unroll
                for (int n = 0; n < 2; n++)
                    acc[m][n] = __builtin_amdgcn_mfma_f32_16x16x32_bf16(wf[m], xf[n], acc[m][n], 0, 0, 0);
        }
        if (more) {
            const int nxt = cur ^ 1;
            if (tid < 256) *(u16x8*)(ASEC(nxt) + awz) = av;
            asm volatile("s_waitcnt lgkmcnt(0)" ::: "memory");
            __builtin_amdgcn_s_barrier();
            cur = nxt;
        }
    }

    // phase-1 epilogue: hout f32 + Hs bf16 (pre-tiled swizzled image)
#pragma unroll
    for (int n = 0; n < 2; n++) {
        int node = n * 16 + fr;
        long gnode = row0 + node;
#pragma unroll
        for (int m = 0; m < 4; m++) {
            int hc = wv * 64 + m * 16 + hi4;
            f32x4 bv = *(const f32x4*)(b2 + hc);
            f32x4 v = acc[m][n] + bv;
            *(f32x4*)(Hout + gnode * 512 + hc) = v;
            int tt = hc >> 5, sk = (hc & 31) >> 3, e = hc & 7;
            *(bf16x4*)(Hs + tt * 2048 + swz(node, sk) + e * 2) = cvt4(v);
        }
    }
    asm volatile("s_waitcnt lgkmcnt(0)" ::: "memory");
    __builtin_amdgcn_s_barrier();

    // ---- phase 2: gate (barrier-free; Hs complete) ----
    f32x4 acc2[4][2];
#pragma unroll
    for (int m = 0; m < 4; m++)
#pragma unroll
        for (int n = 0; n < 2; n++)
#pragma unroll
            for (int r = 0; r < 4; r++) acc2[m][n][r] = 0.f;

    for (int g = 0; g < 16; g++) {
        const char* bt = Wgp + ((size_t)cbv * 16 + g) * 16384;
        bf16x8 wf[4], xf[2];
#pragma unroll
        for (int m = 0; m < 4; m++)
            wf[m] = *(const bf16x8*)(bt + swz(rbase + m * 16 + fr, sec));
#pragma unroll
        for (int n = 0; n < 2; n++)
            xf[n] = *(const bf16x8*)(Hs + g * 2048 + swz(n * 16 + fr, sec));
#pragma unroll
        for (int m = 0; m < 4; m++)
#pragma unroll
            for (int n = 0; n < 2; n++)
                acc2[m][n] = __builtin_amdgcn_mfma_f32_16x16x32_bf16(wf[m], xf[n], acc2[m][n], 0, 0, 0);
    }
#undef ASEC

    // epilogue 2: tanh + Wa dot, reduce over gate cols
#pragma unroll
    for (int n = 0; n < 2; n++) {
        float s = 0.f;
#pragma unroll
        for (int m = 0; m < 4; m++) {
            int gc = wv * 64 + m * 16 + hi4;
            f32x4 bgv = *(const f32x4*)(bg + gc);
            f32x4 wav = *(const f32x4*)(Wa + gc);
#pragma unroll
            for (int r = 0; r < 4; r++)
                s += tanhf(acc2[m][n][r] + bgv[r]) * wav[r];
        }
        s += __shfl_xor(s, 16, 64);
        s += __shfl_xor(s, 32, 64);
        if (sec == 0) atomicAdd(&aS[n * 16 + fr], s);
    }
    __syncthreads();
    if (tid < 32) alpha[row0 + tid] = aS[tid];
}

// ---------- softmax over 20000 scalars (ba cancels) ----------
__global__ __launch_bounds__(1024) void softmax_kernel(const float* __restrict__ alpha,
                                                       float* __restrict__ att, int N) {
    __shared__ float red[16];
    __shared__ float bc[2];
    int tid = threadIdx.x, lane = tid & 63, wv = tid >> 6;
    float m = -3.4e38f;
    for (int i = tid; i < N; i += 1024) m = fmaxf(m, alpha[i]);
#pragma unroll
    for (int o = 32; o > 0; o >>= 1) m = fmaxf(m, __shfl_xor(m, o, 64));
    if (lane == 0) red[wv] = m;
    __syncthreads();
    if (tid == 0) {
        float mm = red[0];
        for (int i = 1; i < 16; i++) mm = fmaxf(mm, red[i]);
        bc[0] = mm;
    }
    __syncthreads();
    float Mx = bc[0];
    float s = 0.f;
    for (int i = tid; i < N; i += 1024) s += expf(alpha[i] - Mx);
#pragma unroll
    for (int o = 32; o > 0; o >>= 1) s += __shfl_xor(s, o, 64);
    if (lane == 0) red[wv] = s;
    __syncthreads();
    if (tid == 0) {
        float ss = 0.f;
        for (int i = 0; i < 16; i++) ss += red[i];
        bc[1] = ss;
    }
    __syncthreads();
    float inv = 1.f / bc[1];
    for (int i = tid; i < N; i += 1024) att[i] = expf(alpha[i] - Mx) * inv;
}

// ---------- launch ----------
extern "C" void kernel_launch(void* const* d_in, const int* in_sizes, int n_in,
                              void* d_out, int out_size, void* d_ws, size_t ws_size,
                              hipStream_t stream) {
    const float* x  = (const float*)d_in[0];
    const int*   ei = (const int*)d_in[1];     // [2][160000]: src then dst
    const float* W1 = (const float*)d_in[2];
    const float* b1 = (const float*)d_in[3];
    const float* W2 = (const float*)d_in[4];
    const float* b2 = (const float*)d_in[5];
    const float* Wg = (const float*)d_in[6];
    const float* bg = (const float*)d_in[7];
    const float* Wa = (const float*)d_in[8];
    // d_in[9] = ba: cancels in softmax, unused.

    const int M = 20000, IN = 2048, H = 512, E = 160000;

    char* ws = (char*)d_ws;
    __bf16* ybf   = (__bf16*)ws;                // 20,480,000
    char*  W1p    = ws + 20480000;              //  2,097,152
    char*  W2p    = ws + 22577152;              //    524,288
    char*  Wgp    = ws + 23101440;              //    524,288
    __bf16* h1b   = (__bf16*)(ws + 23625728);   // 20,480,000
    float* alpha  = (float*)(ws + 44105728);    //     80,000
    int*   counts = (int*)(ws + 44185728);      //     80,000
    int*   offs   = (int*)(ws + 44265728);      //     80,004
    int*   cursor = (int*)(ws + 44345732);      //     80,000
    int*   eids   = (int*)(ws + 44425732);      //    640,000

    float* hout = (float*)d_out;                 // [20000][512] f32
    float* att  = hout + (size_t)M * H;          // [20000] f32

    // weights -> pre-tiled + pre-swizzled images (bf16)
    convw_pre_kernel<<<4096, 256, 0, stream>>>(W1, W1p, IN);
    convw_pre_kernel<<<1024, 256, 0, stream>>>(W2, W2p, H);
    convw_pre_kernel<<<1024, 256, 0, stream>>>(Wg, Wgp, H);

    // CSR build by dst
    hipMemsetAsync(counts, 0, M * 4, stream);
    count_kernel<<<(E + 255) / 256, 256, 0, stream>>>(ei + E, counts, E);
    scan_kernel<<<1, 1024, 0, stream>>>(counts, offs, M);
    hipMemsetAsync(cursor, 0, M * 4, stream);
    bucket_kernel<<<(E + 255) / 256, 256, 0, stream>>>(ei, ei + E, offs, cursor, eids, E);

    // y = bf16(x @ W1)   (BM=32, grid 625x2 exact, no B staging)
    gemm1_kernel<<<dim3(625, 2), 256, 0, stream>>>(x, W1p, ybf);

    // h1 = bf16(relu(y_self + gather(y) + b1))   (one wave per node)
    gather_h1_kernel<<<5000, 256, 0, stream>>>(ybf, offs, eids, b1, h1b);

    // h = h1@W2+b2 -> d_out, fused alpha = rowsum(tanh(h@Wg+bg)*Wa)
    mlp23_kernel<<<625, 512, 0, stream>>>(h1b, W2p, b2, Wgp, bg, Wa, hout, alpha);

    // att = softmax(alpha)
    softmax_kernel<<<1, 1024, 0, stream>>>(alpha, att, M);
}

// Round 11
// 290.086 us; speedup vs baseline: 1.1482x; 1.0969x over previous
//
#include <hip/hip_runtime.h>

// ---------- types ----------
typedef __attribute__((ext_vector_type(8))) __bf16 bf16x8;
typedef __attribute__((ext_vector_type(4))) __bf16 bf16x4;
typedef __attribute__((ext_vector_type(4))) float f32x4;
typedef __attribute__((ext_vector_type(8))) unsigned short u16x8;

// native casts -> v_cvt_pk_bf16_f32 (RNE) on gfx950
__device__ __forceinline__ bf16x8 cvt8(float4 a, float4 b) {
    bf16x8 o;
    o[0] = (__bf16)a.x; o[1] = (__bf16)a.y; o[2] = (__bf16)a.z; o[3] = (__bf16)a.w;
    o[4] = (__bf16)b.x; o[5] = (__bf16)b.y; o[6] = (__bf16)b.z; o[7] = (__bf16)b.w;
    return o;
}
__device__ __forceinline__ bf16x4 cvt4(f32x4 v) {
    bf16x4 o;
    o[0] = (__bf16)v[0]; o[1] = (__bf16)v[1]; o[2] = (__bf16)v[2]; o[3] = (__bf16)v[3];
    return o;
}

// m201 st_16x32 swizzle on 64B rows: flips byte-bit5 with row-bit3.
__device__ __forceinline__ unsigned swz(int row, int s) {
    return (unsigned)((row * 64 + s * 16) ^ ((row & 8) << 2));
}

// ---------- W [K][N=512] f32 -> pre-tiled + pre-swizzled bf16 image ----------
__global__ __launch_bounds__(256) void convw_pre_kernel(const float* __restrict__ W,
                                                        char* __restrict__ out, int K) {
    int t = blockIdx.x * 256 + threadIdx.x;
    if (t >= K * 512) return;
    int k = t >> 9, n = t & 511;
    int cb = n >> 8, r = n & 255, tt = k >> 5, s = (k & 31) >> 3, e = k & 7;
    size_t off = ((size_t)cb * (K >> 5) + tt) * 16384 + swz(r, s) + e * 2;
    *(__bf16*)(out + off) = (__bf16)W[t];
}

// ---------- CSR build (by dst) ----------
__global__ __launch_bounds__(256) void count_kernel(const int* __restrict__ dst,
                                                    int* __restrict__ counts, int E) {
    int e = blockIdx.x * 256 + threadIdx.x;
    if (e < E) atomicAdd(&counts[dst[e]], 1);
}

__global__ __launch_bounds__(1024) void scan_kernel(const int* __restrict__ counts,
                                                    int* __restrict__ offs, int N) {
    __shared__ int wsum[16], wpre[16];
    const int CH = 20;
    int tid = threadIdx.x, lane = tid & 63, wv = tid >> 6;
    int base = tid * CH;
    int s = 0;
    for (int i = 0; i < CH; i++) { int idx = base + i; s += (idx < N) ? counts[idx] : 0; }
    int run = s;
#pragma unroll
    for (int o = 1; o < 64; o <<= 1) { int v = __shfl_up(run, o, 64); if (lane >= o) run += v; }
    if (lane == 63) wsum[wv] = run;
    __syncthreads();
    if (tid == 0) { int acc = 0; for (int w = 0; w < 16; w++) { wpre[w] = acc; acc += wsum[w]; } }
    __syncthreads();
    int pre = wpre[wv] + (run - s);
    for (int i = 0; i < CH; i++) {
        int idx = base + i;
        if (idx <= N) offs[idx] = pre;
        pre += (idx < N) ? counts[idx] : 0;
    }
}

__global__ __launch_bounds__(256) void bucket_kernel(const int* __restrict__ src,
                                                     const int* __restrict__ dst,
                                                     const int* __restrict__ offs,
                                                     int* __restrict__ cursor,
                                                     int* __restrict__ eids, int E) {
    int e = blockIdx.x * 256 + threadIdx.x;
    if (e >= E) return;
    int d = dst[e];
    int pos = atomicAdd(&cursor[d], 1);
    eids[offs[d] + pos] = src[e];
}

// ---------- y = y0 + y1 (bf16 K-split partial merge) ----------
__global__ __launch_bounds__(256) void addy_kernel(const __bf16* __restrict__ y0,
                                                   const __bf16* __restrict__ y1,
                                                   __bf16* __restrict__ y) {
    size_t i = ((size_t)blockIdx.x * 256 + threadIdx.x) * 8;
    bf16x8 a = *(const bf16x8*)(y0 + i);
    bf16x8 b = *(const bf16x8*)(y1 + i);
    bf16x8 o;
#pragma unroll
    for (int j = 0; j < 8; j++) o[j] = (__bf16)((float)a[j] + (float)b[j]);
    *(bf16x8*)(y + i) = o;
}

// ---------- gather + h1 (y bf16): one wave per node, 16B/lane ----------
__global__ __launch_bounds__(256) void gather_h1_kernel(const __bf16* __restrict__ y,
                                                        const int* __restrict__ offs,
                                                        const int* __restrict__ eids,
                                                        const float* __restrict__ b1,
                                                        __bf16* __restrict__ h1b) {
    const int node = blockIdx.x * 4 + (threadIdx.x >> 6);
    const int c = (threadIdx.x & 63) * 8;
    float s[8];
    bf16x8 v = *(const bf16x8*)(y + (size_t)node * 512 + c);
#pragma unroll
    for (int j = 0; j < 8; j++) s[j] = (float)v[j];
    const int beg = offs[node], end = offs[node + 1];   // wave-uniform
    for (int k = beg; k < end; k++) {
        int sn = eids[k];
        bf16x8 u = *(const bf16x8*)(y + (size_t)sn * 512 + c);
#pragma unroll
        for (int j = 0; j < 8; j++) s[j] += (float)u[j];
    }
    bf16x8 o;
#pragma unroll
    for (int j = 0; j < 8; j++) o[j] = (__bf16)fmaxf(s[j] + b1[c + j], 0.f);
    *(bf16x8*)(h1b + (size_t)node * 512 + c) = o;
}

// =====================================================================
// GEMM1 (K-split): Ypart[kh][20000][512](bf16) = X[:, kh*1024 : +1024] @ W1-half
// 256 thr (4 waves), BM=64, BN=256 (grid.y), kh=grid.z. 16 outer iters, BK=64.
// R8-proven inner loop: A LDS dbuf 2x8KB (conflict-free ar_=tid>>2 staging,
// st_16x32 swizzle), B direct from pre-tiled L2 image, lgkmcnt-only barriers.
// Swapped MFMA: D = Wfrag*Afrag; node=lane&15, weightcol=(lane>>4)*4+r.
// =====================================================================
__global__ __launch_bounds__(256) void gemm1_kernel(const float* __restrict__ X,
                                                    const char* __restrict__ Bpre,
                                                    __bf16* __restrict__ Ybase, int M) {
    constexpr int KDIM = 2048, NT2 = 16;   // 16 outer iters x 64K = 1024 per half
    __shared__ char smem[16384];
    const int tid = threadIdx.x, lane = tid & 63, wv = tid >> 6;
    const int fr = lane & 15, sec = lane >> 4, hi4 = (lane >> 4) * 4;
    const long row0 = (long)blockIdx.x * 64;
    const int kh = blockIdx.z;
    const char* Bp = Bpre + ((size_t)blockIdx.y * 64 + (size_t)kh * 32) * 16384;
    __bf16* Y = Ybase + (size_t)kh * 10240000;   // 20000*512 per partial

    f32x4 acc[4][4];
#pragma unroll
    for (int m = 0; m < 4; m++)
#pragma unroll
        for (int n = 0; n < 4; n++)
#pragma unroll
            for (int r = 0; r < 4; r++) acc[m][n][r] = 0.f;

    const int ar_ = tid >> 2, ks = tid & 3;
    const unsigned awz = swz(ar_, ks);
    long arow = row0 + ar_; if (arow > (long)M - 1) arow = M - 1;
    const float* Ap = X + arow * KDIM + kh * 1024;

#define ASEC(b) (smem + (b) * 8192)
#define LOAD_A4(d0, d1, d2, d3, t) do {                      \
        const float* p_ = Ap + (t) * 64 + ks * 8;            \
        d0 = *(const float4*)(p_);                           \
        d1 = *(const float4*)(p_ + 4);                       \
        d2 = *(const float4*)(p_ + 32);                      \
        d3 = *(const float4*)(p_ + 36);                      \
    } while (0)

    {   // prologue
        float4 a0, a1, a2, a3;
        LOAD_A4(a0, a1, a2, a3, 0);
        *(bf16x8*)(ASEC(0) + awz) = cvt8(a0, a1);
        *(bf16x8*)(ASEC(0) + 4096 + awz) = cvt8(a2, a3);
    }
    asm volatile("s_waitcnt lgkmcnt(0)" ::: "memory");
    __builtin_amdgcn_s_barrier();

    int cur = 0;
    for (int tt = 0; tt < NT2; tt++) {
        const bool more = (tt + 1 < NT2);
        float4 a0, a1, a2, a3;
        if (more) LOAD_A4(a0, a1, a2, a3, tt + 1);   // issue early
#pragma unroll
        for (int h = 0; h < 2; h++) {
            const char* bt = Bp + (size_t)(tt * 2 + h) * 16384;
            bf16x8 wf[4], xf[4];
#pragma unroll
            for (int m = 0; m < 4; m++)
                wf[m] = *(const bf16x8*)(bt + swz(wv * 64 + m * 16 + fr, sec));  // L2
#pragma unroll
            for (int n = 0; n < 4; n++)
                xf[n] = *(const bf16x8*)(ASEC(cur) + h * 4096 + swz(n * 16 + fr, sec));
#pragma unroll
            for (int m = 0; m < 4; m++)
#pragma unroll
                for (int n = 0; n < 4; n++)
                    acc[m][n] = __builtin_amdgcn_mfma_f32_16x16x32_bf16(wf[m], xf[n], acc[m][n], 0, 0, 0);
        }
        if (more) {
            const int nxt = cur ^ 1;
            *(bf16x8*)(ASEC(nxt) + awz) = cvt8(a0, a1);
            *(bf16x8*)(ASEC(nxt) + 4096 + awz) = cvt8(a2, a3);
            asm volatile("s_waitcnt lgkmcnt(0)" ::: "memory");
            __builtin_amdgcn_s_barrier();
            cur = nxt;
        }
    }
#undef ASEC
#undef LOAD_A4

    // epilogue: bf16 partial store
#pragma unroll
    for (int n = 0; n < 4; n++) {
        long node = row0 + n * 16 + fr;
        if (node < M) {
#pragma unroll
            for (int m = 0; m < 4; m++) {
                int col = blockIdx.y * 256 + wv * 64 + m * 16 + hi4;
                *(bf16x4*)(Y + node * 512 + col) = cvt4(acc[m][n]);
            }
        }
    }
}

// =====================================================================
// Fused MLP2+gate: h = h1@W2+b2 -> hout (f32) AND h-tile in LDS (bf16,
// pre-tiled swizzled); then alpha[node] = sum_gc tanh(h@Wg+bg)[gc]*Wa[gc].
// 512 thr (8 waves), BM=32 nodes, BN=512. Grid 625 (exact).
// LDS 41216B: A dbuf 2x4KB @0, Hs 16x2KB @8192, aS[32] @40960.
// A-staging: LINEAR LDS write (thread t -> bytes 16t), global src is the
// swizzle-inverse coordinate (rule #21: write-perm == read-perm).
// =====================================================================
__global__ __launch_bounds__(512) void mlp23_kernel(const __bf16* __restrict__ H1,
                                                    const char* __restrict__ W2p,
                                                    const float* __restrict__ b2,
                                                    const char* __restrict__ Wgp,
                                                    const float* __restrict__ bg,
                                                    const float* __restrict__ Wa,
                                                    float* __restrict__ Hout,
                                                    float* __restrict__ alpha) {
    constexpr int NT2 = 8;    // K=512 -> 8 iters (BK=64), 16 k-tiles
    __shared__ char smem[41216];
    char* Hs = smem + 8192;
    float* aS = (float*)(smem + 40960);
    const int tid = threadIdx.x, lane = tid & 63, wv = tid >> 6;
    const int fr = lane & 15, sec = lane >> 4, hi4 = (lane >> 4) * 4;
    const long row0 = (long)blockIdx.x * 32;
    const int cbv = wv >> 2, rbase = (wv & 3) * 64;   // weight image coords

    if (tid < 32) aS[tid] = 0.f;

    // A staging (tid<256): LINEAR write of the 4KB tile at byte 16*tid.
    // Invert swizzle for the global source coordinate.
    const int b16 = tid * 16;
    const int sh = b16 >> 11;             // k-half (0/1) within BK=64
    const int bb = b16 & 2047;
    const int srow = bb >> 6;
    const int soff = bb & 63;
    const int ss = (soff ^ ((srow & 8) << 2)) >> 4;
    const __bf16* ApH = H1 + (row0 + srow) * 512 + sh * 32 + ss * 8;

#define ASEC(b) (smem + (b) * 4096)

    f32x4 acc[4][2];
#pragma unroll
    for (int m = 0; m < 4; m++)
#pragma unroll
        for (int n = 0; n < 2; n++)
#pragma unroll
            for (int r = 0; r < 4; r++) acc[m][n][r] = 0.f;

    // prologue
    if (tid < 256) {
        u16x8 v = *(const u16x8*)(ApH);
        *(u16x8*)(ASEC(0) + b16) = v;
    }
    asm volatile("s_waitcnt lgkmcnt(0)" ::: "memory");
    __builtin_amdgcn_s_barrier();

    // ---- phase 1: h = h1 @ W2 ----
    int cur = 0;
    for (int tt = 0; tt < NT2; tt++) {
        u16x8 av;
        const bool more = (tt + 1 < NT2);
        if (more && tid < 256) av = *(const u16x8*)(ApH + (tt + 1) * 64);
#pragma unroll
        for (int h = 0; h < 2; h++) {
            const char* bt = W2p + ((size_t)cbv * 16 + tt * 2 + h) * 16384;
            bf16x8 wf[4], xf[2];
#pragma unroll
            for (int m = 0; m < 4; m++)
                wf[m] = *(const bf16x8*)(bt + swz(rbase + m * 16 + fr, sec));
#pragma unroll
            for (int n = 0; n < 2; n++)
                xf[n] = *(const bf16x8*)(ASEC(cur) + h * 2048 + swz(n * 16 + fr, sec));
#pragma unroll
            for (int m = 0; m < 4; m++)
#pragma unroll
                for (int n = 0; n < 2; n++)
                    acc[m][n] = __builtin_amdgcn_mfma_f32_16x16x32_bf16(wf[m], xf[n], acc[m][n], 0, 0, 0);
        }
        if (more) {
            const int nxt = cur ^ 1;
            if (tid < 256) *(u16x8*)(ASEC(nxt) + b16) = av;
            asm volatile("s_waitcnt lgkmcnt(0)" ::: "memory");
            __builtin_amdgcn_s_barrier();
            cur = nxt;
        }
    }

    // phase-1 epilogue: hout f32 + Hs bf16 (pre-tiled swizzled image)
#pragma unroll
    for (int n = 0; n < 2; n++) {
        int node = n * 16 + fr;
        long gnode = row0 + node;
#pragma unroll
        for (int m = 0; m < 4; m++) {
            int hc = wv * 64 + m * 16 + hi4;
            f32x4 bv = *(const f32x4*)(b2 + hc);
            f32x4 v = acc[m][n] + bv;
            *(f32x4*)(Hout + gnode * 512 + hc) = v;
            int tt = hc >> 5, sk = (hc & 31) >> 3, e = hc & 7;
            *(bf16x4*)(Hs + tt * 2048 + swz(node, sk) + e * 2) = cvt4(v);
        }
    }
    asm volatile("s_waitcnt lgkmcnt(0)" ::: "memory");
    __builtin_amdgcn_s_barrier();

    // ---- phase 2: gate (barrier-free; Hs complete) ----
    f32x4 acc2[4][2];
#pragma unroll
    for (int m = 0; m < 4; m++)
#pragma unroll
        for (int n = 0; n < 2; n++)
#pragma unroll
            for (int r = 0; r < 4; r++) acc2[m][n][r] = 0.f;

    for (int g = 0; g < 16; g++) {
        const char* bt = Wgp + ((size_t)cbv * 16 + g) * 16384;
        bf16x8 wf[4], xf[2];
#pragma unroll
        for (int m = 0; m < 4; m++)
            wf[m] = *(const bf16x8*)(bt + swz(rbase + m * 16 + fr, sec));
#pragma unroll
        for (int n = 0; n < 2; n++)
            xf[n] = *(const bf16x8*)(Hs + g * 2048 + swz(n * 16 + fr, sec));
#pragma unroll
        for (int m = 0; m < 4; m++)
#pragma unroll
            for (int n = 0; n < 2; n++)
                acc2[m][n] = __builtin_amdgcn_mfma_f32_16x16x32_bf16(wf[m], xf[n], acc2[m][n], 0, 0, 0);
    }
#undef ASEC

    // epilogue 2: tanh + Wa dot, reduce over gate cols
#pragma unroll
    for (int n = 0; n < 2; n++) {
        float s = 0.f;
#pragma unroll
        for (int m = 0; m < 4; m++) {
            int gc = wv * 64 + m * 16 + hi4;
            f32x4 bgv = *(const f32x4*)(bg + gc);
            f32x4 wav = *(const f32x4*)(Wa + gc);
#pragma unroll
            for (int r = 0; r < 4; r++)
                s += tanhf(acc2[m][n][r] + bgv[r]) * wav[r];
        }
        s += __shfl_xor(s, 16, 64);
        s += __shfl_xor(s, 32, 64);
        if (sec == 0) atomicAdd(&aS[n * 16 + fr], s);
    }
    __syncthreads();
    if (tid < 32) alpha[row0 + tid] = aS[tid];
}

// ---------- softmax over 20000 scalars (ba cancels) ----------
__global__ __launch_bounds__(1024) void softmax_kernel(const float* __restrict__ alpha,
                                                       float* __restrict__ att, int N) {
    __shared__ float red[16];
    __shared__ float bc[2];
    int tid = threadIdx.x, lane = tid & 63, wv = tid >> 6;
    float m = -3.4e38f;
    for (int i = tid; i < N; i += 1024) m = fmaxf(m, alpha[i]);
#pragma unroll
    for (int o = 32; o > 0; o >>= 1) m = fmaxf(m, __shfl_xor(m, o, 64));
    if (lane == 0) red[wv] = m;
    __syncthreads();
    if (tid == 0) {
        float mm = red[0];
        for (int i = 1; i < 16; i++) mm = fmaxf(mm, red[i]);
        bc[0] = mm;
    }
    __syncthreads();
    float Mx = bc[0];
    float s = 0.f;
    for (int i = tid; i < N; i += 1024) s += expf(alpha[i] - Mx);
#pragma unroll
    for (int o = 32; o > 0; o >>= 1) s += __shfl_xor(s, o, 64);
    if (lane == 0) red[wv] = s;
    __syncthreads();
    if (tid == 0) {
        float ss = 0.f;
        for (int i = 0; i < 16; i++) ss += red[i];
        bc[1] = ss;
    }
    __syncthreads();
    float inv = 1.f / bc[1];
    for (int i = tid; i < N; i += 1024) att[i] = expf(alpha[i] - Mx) * inv;
}

// ---------- launch ----------
extern "C" void kernel_launch(void* const* d_in, const int* in_sizes, int n_in,
                              void* d_out, int out_size, void* d_ws, size_t ws_size,
                              hipStream_t stream) {
    const float* x  = (const float*)d_in[0];
    const int*   ei = (const int*)d_in[1];     // [2][160000]: src then dst
    const float* W1 = (const float*)d_in[2];
    const float* b1 = (const float*)d_in[3];
    const float* W2 = (const float*)d_in[4];
    const float* b2 = (const float*)d_in[5];
    const float* Wg = (const float*)d_in[6];
    const float* bg = (const float*)d_in[7];
    const float* Wa = (const float*)d_in[8];
    // d_in[9] = ba: cancels in softmax, unused.

    const int M = 20000, IN = 2048, H = 512, E = 160000;

    char* ws = (char*)d_ws;
    __bf16* yp    = (__bf16*)ws;                // partials: 2 x 20,480,000
    __bf16* ysum  = (__bf16*)(ws + 40960000);   // 20,480,000
    char*  W1p    = ws + 61440000;              //  2,097,152
    char*  W2p    = ws + 63537152;              //    524,288
    char*  Wgp    = ws + 64061440;              //    524,288
    __bf16* h1b   = (__bf16*)(ws + 64585728);   // 20,480,000
    float* alpha  = (float*)(ws + 85065728);    //     80,000
    int*   counts = (int*)(ws + 85145728);      //     80,000
    int*   offs   = (int*)(ws + 85225728);      //     80,004
    int*   cursor = (int*)(ws + 85305732);      //     80,000
    int*   eids   = (int*)(ws + 85385732);      //    640,000

    float* hout = (float*)d_out;                 // [20000][512] f32
    float* att  = hout + (size_t)M * H;          // [20000] f32

    // weights -> pre-tiled + pre-swizzled images (bf16)
    convw_pre_kernel<<<4096, 256, 0, stream>>>(W1, W1p, IN);
    convw_pre_kernel<<<1024, 256, 0, stream>>>(W2, W2p, H);
    convw_pre_kernel<<<1024, 256, 0, stream>>>(Wg, Wgp, H);

    // CSR build by dst
    hipMemsetAsync(counts, 0, M * 4, stream);
    count_kernel<<<(E + 255) / 256, 256, 0, stream>>>(ei + E, counts, E);
    scan_kernel<<<1, 1024, 0, stream>>>(counts, offs, M);
    hipMemsetAsync(cursor, 0, M * 4, stream);
    bucket_kernel<<<(E + 255) / 256, 256, 0, stream>>>(ei, ei + E, offs, cursor, eids, E);

    // y partials = x @ W1 (K-split over blockIdx.z), then merge
    gemm1_kernel<<<dim3(313, 2, 2), 256, 0, stream>>>(x, W1p, yp, M);
    addy_kernel<<<5000, 256, 0, stream>>>(yp, yp + 10240000, ysum);

    // h1 = bf16(relu(y_self + gather(y) + b1))   (one wave per node)
    gather_h1_kernel<<<5000, 256, 0, stream>>>(ysum, offs, eids, b1, h1b);

    // h = h1@W2+b2 -> d_out, fused alpha = rowsum(tanh(h@Wg+bg)*Wa)
    mlp23_kernel<<<625, 512, 0, stream>>>(h1b, W2p, b2, Wgp, bg, Wa, hout, alpha);

    // att = softmax(alpha)
    softmax_kernel<<<1, 1024, 0, stream>>>(alpha, att, M);
}

// Round 12
// 288.424 us; speedup vs baseline: 1.1548x; 1.0058x over previous
//
#include <hip/hip_runtime.h>

// ---------- types ----------
typedef __attribute__((ext_vector_type(8))) __bf16 bf16x8;
typedef __attribute__((ext_vector_type(4))) __bf16 bf16x4;
typedef __attribute__((ext_vector_type(4))) float f32x4;
typedef __attribute__((ext_vector_type(8))) unsigned short u16x8;

// native casts -> v_cvt_pk_bf16_f32 (RNE) on gfx950
__device__ __forceinline__ bf16x8 cvt8(float4 a, float4 b) {
    bf16x8 o;
    o[0] = (__bf16)a.x; o[1] = (__bf16)a.y; o[2] = (__bf16)a.z; o[3] = (__bf16)a.w;
    o[4] = (__bf16)b.x; o[5] = (__bf16)b.y; o[6] = (__bf16)b.z; o[7] = (__bf16)b.w;
    return o;
}
__device__ __forceinline__ bf16x4 cvt4(f32x4 v) {
    bf16x4 o;
    o[0] = (__bf16)v[0]; o[1] = (__bf16)v[1]; o[2] = (__bf16)v[2]; o[3] = (__bf16)v[3];
    return o;
}

// m201 st_16x32 swizzle on 64B rows: flips byte-bit5 with row-bit3.
__device__ __forceinline__ unsigned swz(int row, int s) {
    return (unsigned)((row * 64 + s * 16) ^ ((row & 8) << 2));
}

// ---------- W [K][N=512] f32 -> pre-tiled + pre-swizzled bf16 image ----------
__global__ __launch_bounds__(256) void convw_pre_kernel(const float* __restrict__ W,
                                                        char* __restrict__ out, int K) {
    int t = blockIdx.x * 256 + threadIdx.x;
    if (t >= K * 512) return;
    int k = t >> 9, n = t & 511;
    int cb = n >> 8, r = n & 255, tt = k >> 5, s = (k & 31) >> 3, e = k & 7;
    size_t off = ((size_t)cb * (K >> 5) + tt) * 16384 + swz(r, s) + e * 2;
    *(__bf16*)(out + off) = (__bf16)W[t];
}

// ---------- CSR build (by dst) ----------
__global__ __launch_bounds__(256) void count_kernel(const int* __restrict__ dst,
                                                    int* __restrict__ counts, int E) {
    int e = blockIdx.x * 256 + threadIdx.x;
    if (e < E) atomicAdd(&counts[dst[e]], 1);
}

__global__ __launch_bounds__(1024) void scan_kernel(const int* __restrict__ counts,
                                                    int* __restrict__ offs, int N) {
    __shared__ int wsum[16], wpre[16];
    const int CH = 20;
    int tid = threadIdx.x, lane = tid & 63, wv = tid >> 6;
    int base = tid * CH;
    int s = 0;
    for (int i = 0; i < CH; i++) { int idx = base + i; s += (idx < N) ? counts[idx] : 0; }
    int run = s;
#pragma unroll
    for (int o = 1; o < 64; o <<= 1) { int v = __shfl_up(run, o, 64); if (lane >= o) run += v; }
    if (lane == 63) wsum[wv] = run;
    __syncthreads();
    if (tid == 0) { int acc = 0; for (int w = 0; w < 16; w++) { wpre[w] = acc; acc += wsum[w]; } }
    __syncthreads();
    int pre = wpre[wv] + (run - s);
    for (int i = 0; i < CH; i++) {
        int idx = base + i;
        if (idx <= N) offs[idx] = pre;
        pre += (idx < N) ? counts[idx] : 0;
    }
}

__global__ __launch_bounds__(256) void bucket_kernel(const int* __restrict__ src,
                                                     const int* __restrict__ dst,
                                                     const int* __restrict__ offs,
                                                     int* __restrict__ cursor,
                                                     int* __restrict__ eids, int E) {
    int e = blockIdx.x * 256 + threadIdx.x;
    if (e >= E) return;
    int d = dst[e];
    int pos = atomicAdd(&cursor[d], 1);
    eids[offs[d] + pos] = src[e];
}

// ---------- y = p0+p1+p2+p3 (bf16 K-quarter partial merge) ----------
__global__ __launch_bounds__(256) void addy4_kernel(const __bf16* __restrict__ p,
                                                    __bf16* __restrict__ y) {
    size_t i = ((size_t)blockIdx.x * 256 + threadIdx.x) * 8;
    bf16x8 a = *(const bf16x8*)(p + i);
    bf16x8 b = *(const bf16x8*)(p + 10240000 + i);
    bf16x8 c = *(const bf16x8*)(p + 20480000 + i);
    bf16x8 d = *(const bf16x8*)(p + 30720000 + i);
    bf16x8 o;
#pragma unroll
    for (int j = 0; j < 8; j++)
        o[j] = (__bf16)(((float)a[j] + (float)b[j]) + ((float)c[j] + (float)d[j]));
    *(bf16x8*)(y + i) = o;
}

// ---------- gather + h1 (y bf16): one wave per node, 16B/lane ----------
__global__ __launch_bounds__(256) void gather_h1_kernel(const __bf16* __restrict__ y,
                                                        const int* __restrict__ offs,
                                                        const int* __restrict__ eids,
                                                        const float* __restrict__ b1,
                                                        __bf16* __restrict__ h1b) {
    const int node = blockIdx.x * 4 + (threadIdx.x >> 6);
    const int c = (threadIdx.x & 63) * 8;
    float s[8];
    bf16x8 v = *(const bf16x8*)(y + (size_t)node * 512 + c);
#pragma unroll
    for (int j = 0; j < 8; j++) s[j] = (float)v[j];
    const int beg = offs[node], end = offs[node + 1];   // wave-uniform
    for (int k = beg; k < end; k++) {
        int sn = eids[k];
        bf16x8 u = *(const bf16x8*)(y + (size_t)sn * 512 + c);
#pragma unroll
        for (int j = 0; j < 8; j++) s[j] += (float)u[j];
    }
    bf16x8 o;
#pragma unroll
    for (int j = 0; j < 8; j++) o[j] = (__bf16)fmaxf(s[j] + b1[c + j], 0.f);
    *(bf16x8*)(h1b + (size_t)node * 512 + c) = o;
}

// =====================================================================
// GEMM1 (barrier-free waves): Ypart[kh] = X[:, kh*512:+512] @ W1-quarter
// 512 thr (8 waves), BM=64 rows, all 512 cols; grid (313, 4=kh).
// Stage: whole 64x512 A-quarter f32 -> 64KB swizzled bf16 LDS image
//   (linear LDS writes, inverse-swizzle global source; ONE barrier).
// Then each wave independently computes its 64x64 tile over 16 k-tiles:
//   4 ds_read_b128 (xf) + 4 L2 reads (wf from pre-tiled image) + 16 MFMAs,
//   NO barriers -> compiler pipelines freely, 16 waves/CU slip-cover stalls.
// __launch_bounds__(512,4): 2 blocks/CU (LDS 64KB x2 = 128 <= 160KB).
// Swapped MFMA: D = Wfrag*Afrag; node=lane&15, weightcol=(lane>>4)*4+r.
// =====================================================================
__global__ __launch_bounds__(512, 4) void gemm1_kernel(const float* __restrict__ X,
                                                       const char* __restrict__ Bpre,
                                                       __bf16* __restrict__ Ybase, int M) {
    extern __shared__ char smem[];   // 65536
    const int tid = threadIdx.x, lane = tid & 63, wv = tid >> 6;
    const int fr = lane & 15, sec = lane >> 4, hi4 = (lane >> 4) * 4;
    const long row0 = (long)blockIdx.x * 64;
    const int kh = blockIdx.y;                         // k-quarter 0..3
    const int cb = wv >> 2, rbase = (wv & 3) * 64;     // wave's col-slab
    const char* Bp = Bpre + ((size_t)cb * 64 + (size_t)kh * 16) * 16384;
    __bf16* Y = Ybase + (size_t)kh * 10240000;

    // ---- stage: 64 rows x 512 k (f32) -> 16 k-tiles x 4KB swizzled image ----
#pragma unroll
    for (int j = 0; j < 8; j++) {
        int b = tid * 16 + j * 8192;
        int tt = b >> 12, bb = b & 4095;
        int row = bb >> 6, soff = bb & 63;
        int s = (soff ^ ((row & 8) << 2)) >> 4;        // inverse swizzle
        long arow = row0 + row; if (arow > (long)M - 1) arow = M - 1;
        const float* p = X + arow * 2048 + kh * 512 + tt * 32 + s * 8;
        float4 a0 = *(const float4*)p;
        float4 a1 = *(const float4*)(p + 4);
        *(bf16x8*)(smem + b) = cvt8(a0, a1);
    }
    __syncthreads();   // the ONLY barrier

    f32x4 acc[4][4];
#pragma unroll
    for (int m = 0; m < 4; m++)
#pragma unroll
        for (int n = 0; n < 4; n++)
#pragma unroll
            for (int r = 0; r < 4; r++) acc[m][n][r] = 0.f;

    for (int tt = 0; tt < 16; tt++) {
        const char* at = smem + tt * 4096;
        const char* bt = Bp + (size_t)tt * 16384;
        bf16x8 wf[4], xf[4];
#pragma unroll
        for (int m = 0; m < 4; m++)
            wf[m] = *(const bf16x8*)(bt + swz(rbase + m * 16 + fr, sec));  // L2
#pragma unroll
        for (int n = 0; n < 4; n++)
            xf[n] = *(const bf16x8*)(at + swz(n * 16 + fr, sec));          // LDS
#pragma unroll
        for (int m = 0; m < 4; m++)
#pragma unroll
            for (int n = 0; n < 4; n++)
                acc[m][n] = __builtin_amdgcn_mfma_f32_16x16x32_bf16(wf[m], xf[n], acc[m][n], 0, 0, 0);
    }

    // epilogue: bf16 partial store (coalesced bf16x4)
#pragma unroll
    for (int n = 0; n < 4; n++) {
        long node = row0 + n * 16 + fr;
        if (node < M) {
#pragma unroll
            for (int m = 0; m < 4; m++) {
                int col = cb * 256 + rbase + m * 16 + hi4;
                *(bf16x4*)(Y + node * 512 + col) = cvt4(acc[m][n]);
            }
        }
    }
}

// =====================================================================
// Fused MLP2+gate: h = h1@W2+b2 -> hout (f32) AND h-tile in LDS (bf16,
// pre-tiled swizzled); then alpha[node] = sum_gc tanh(h@Wg+bg)[gc]*Wa[gc].
// 512 thr (8 waves), BM=32 nodes, BN=512. Grid 625 (exact).
// LDS 41216B: A dbuf 2x4KB @0, Hs 16x2KB @8192, aS[32] @40960.
// =====================================================================
__global__ __launch_bounds__(512) void mlp23_kernel(const __bf16* __restrict__ H1,
                                                    const char* __restrict__ W2p,
                                                    const float* __restrict__ b2,
                                                    const char* __restrict__ Wgp,
                                                    const float* __restrict__ bg,
                                                    const float* __restrict__ Wa,
                                                    float* __restrict__ Hout,
                                                    float* __restrict__ alpha) {
    constexpr int NT2 = 8;    // K=512 -> 8 iters (BK=64), 16 k-tiles
    __shared__ char smem[41216];
    char* Hs = smem + 8192;
    float* aS = (float*)(smem + 40960);
    const int tid = threadIdx.x, lane = tid & 63, wv = tid >> 6;
    const int fr = lane & 15, sec = lane >> 4, hi4 = (lane >> 4) * 4;
    const long row0 = (long)blockIdx.x * 32;
    const int cbv = wv >> 2, rbase = (wv & 3) * 64;   // weight image coords

    if (tid < 32) aS[tid] = 0.f;

    // A staging (tid<256): LINEAR write at byte 16*tid; inverse-swizzle source.
    const int b16 = tid * 16;
    const int sh = b16 >> 11;             // k-half (0/1) within BK=64
    const int bb = b16 & 2047;
    const int srow = bb >> 6;
    const int soff = bb & 63;
    const int ss = (soff ^ ((srow & 8) << 2)) >> 4;
    const __bf16* ApH = H1 + (row0 + srow) * 512 + sh * 32 + ss * 8;

#define ASEC(b) (smem + (b) * 4096)

    f32x4 acc[4][2];
#pragma unroll
    for (int m = 0; m < 4; m++)
#pragma unroll
        for (int n = 0; n < 2; n++)
#pragma unroll
            for (int r = 0; r < 4; r++) acc[m][n][r] = 0.f;

    // prologue
    if (tid < 256) {
        u16x8 v = *(const u16x8*)(ApH);
        *(u16x8*)(ASEC(0) + b16) = v;
    }
    asm volatile("s_waitcnt lgkmcnt(0)" ::: "memory");
    __builtin_amdgcn_s_barrier();

    // ---- phase 1: h = h1 @ W2 ----
    int cur = 0;
    for (int tt = 0; tt < NT2; tt++) {
        u16x8 av;
        const bool more = (tt + 1 < NT2);
        if (more && tid < 256) av = *(const u16x8*)(ApH + (tt + 1) * 64);
#pragma unroll
        for (int h = 0; h < 2; h++) {
            const char* bt = W2p + ((size_t)cbv * 16 + tt * 2 + h) * 16384;
            bf16x8 wf[4], xf[2];
#pragma unroll
            for (int m = 0; m < 4; m++)
                wf[m] = *(const bf16x8*)(bt + swz(rbase + m * 16 + fr, sec));
#pragma unroll
            for (int n = 0; n < 2; n++)
                xf[n] = *(const bf16x8*)(ASEC(cur) + h * 2048 + swz(n * 16 + fr, sec));
#pragma unroll
            for (int m = 0; m < 4; m++)
#pragma unroll
                for (int n = 0; n < 2; n++)
                    acc[m][n] = __builtin_amdgcn_mfma_f32_16x16x32_bf16(wf[m], xf[n], acc[m][n], 0, 0, 0);
        }
        if (more) {
            const int nxt = cur ^ 1;
            if (tid < 256) *(u16x8*)(ASEC(nxt) + b16) = av;
            asm volatile("s_waitcnt lgkmcnt(0)" ::: "memory");
            __builtin_amdgcn_s_barrier();
            cur = nxt;
        }
    }

    // phase-1 epilogue: hout f32 + Hs bf16 (pre-tiled swizzled image)
#pragma unroll
    for (int n = 0; n < 2; n++) {
        int node = n * 16 + fr;
        long gnode = row0 + node;
#pragma unroll
        for (int m = 0; m < 4; m++) {
            int hc = wv * 64 + m * 16 + hi4;
            f32x4 bv = *(const f32x4*)(b2 + hc);
            f32x4 v = acc[m][n] + bv;
            *(f32x4*)(Hout + gnode * 512 + hc) = v;
            int tt = hc >> 5, sk = (hc & 31) >> 3, e = hc & 7;
            *(bf16x4*)(Hs + tt * 2048 + swz(node, sk) + e * 2) = cvt4(v);
        }
    }
    asm volatile("s_waitcnt lgkmcnt(0)" ::: "memory");
    __builtin_amdgcn_s_barrier();

    // ---- phase 2: gate (barrier-free; Hs complete) ----
    f32x4 acc2[4][2];
#pragma unroll
    for (int m = 0; m < 4; m++)
#pragma unroll
        for (int n = 0; n < 2; n++)
#pragma unroll
            for (int r = 0; r < 4; r++) acc2[m][n][r] = 0.f;

    for (int g = 0; g < 16; g++) {
        const char* bt = Wgp + ((size_t)cbv * 16 + g) * 16384;
        bf16x8 wf[4], xf[2];
#pragma unroll
        for (int m = 0; m < 4; m++)
            wf[m] = *(const bf16x8*)(bt + swz(rbase + m * 16 + fr, sec));
#pragma unroll
        for (int n = 0; n < 2; n++)
            xf[n] = *(const bf16x8*)(Hs + g * 2048 + swz(n * 16 + fr, sec));
#pragma unroll
        for (int m = 0; m < 4; m++)
#pragma unroll
            for (int n = 0; n < 2; n++)
                acc2[m][n] = __builtin_amdgcn_mfma_f32_16x16x32_bf16(wf[m], xf[n], acc2[m][n], 0, 0, 0);
    }
#undef ASEC

    // epilogue 2: tanh + Wa dot, reduce over gate cols
#pragma unroll
    for (int n = 0; n < 2; n++) {
        float s = 0.f;
#pragma unroll
        for (int m = 0; m < 4; m++) {
            int gc = wv * 64 + m * 16 + hi4;
            f32x4 bgv = *(const f32x4*)(bg + gc);
            f32x4 wav = *(const f32x4*)(Wa + gc);
#pragma unroll
            for (int r = 0; r < 4; r++)
                s += tanhf(acc2[m][n][r] + bgv[r]) * wav[r];
        }
        s += __shfl_xor(s, 16, 64);
        s += __shfl_xor(s, 32, 64);
        if (sec == 0) atomicAdd(&aS[n * 16 + fr], s);
    }
    __syncthreads();
    if (tid < 32) alpha[row0 + tid] = aS[tid];
}

// ---------- softmax over 20000 scalars (ba cancels) ----------
__global__ __launch_bounds__(1024) void softmax_kernel(const float* __restrict__ alpha,
                                                       float* __restrict__ att, int N) {
    __shared__ float red[16];
    __shared__ float bc[2];
    int tid = threadIdx.x, lane = tid & 63, wv = tid >> 6;
    float m = -3.4e38f;
    for (int i = tid; i < N; i += 1024) m = fmaxf(m, alpha[i]);
#pragma unroll
    for (int o = 32; o > 0; o >>= 1) m = fmaxf(m, __shfl_xor(m, o, 64));
    if (lane == 0) red[wv] = m;
    __syncthreads();
    if (tid == 0) {
        float mm = red[0];
        for (int i = 1; i < 16; i++) mm = fmaxf(mm, red[i]);
        bc[0] = mm;
    }
    __syncthreads();
    float Mx = bc[0];
    float s = 0.f;
    for (int i = tid; i < N; i += 1024) s += expf(alpha[i] - Mx);
#pragma unroll
    for (int o = 32; o > 0; o >>= 1) s += __shfl_xor(s, o, 64);
    if (lane == 0) red[wv] = s;
    __syncthreads();
    if (tid == 0) {
        float ss = 0.f;
        for (int i = 0; i < 16; i++) ss += red[i];
        bc[1] = ss;
    }
    __syncthreads();
    float inv = 1.f / bc[1];
    for (int i = tid; i < N; i += 1024) att[i] = expf(alpha[i] - Mx) * inv;
}

// ---------- launch ----------
extern "C" void kernel_launch(void* const* d_in, const int* in_sizes, int n_in,
                              void* d_out, int out_size, void* d_ws, size_t ws_size,
                              hipStream_t stream) {
    const float* x  = (const float*)d_in[0];
    const int*   ei = (const int*)d_in[1];     // [2][160000]: src then dst
    const float* W1 = (const float*)d_in[2];
    const float* b1 = (const float*)d_in[3];
    const float* W2 = (const float*)d_in[4];
    const float* b2 = (const float*)d_in[5];
    const float* Wg = (const float*)d_in[6];
    const float* bg = (const float*)d_in[7];
    const float* Wa = (const float*)d_in[8];
    // d_in[9] = ba: cancels in softmax, unused.

    const int M = 20000, IN = 2048, H = 512, E = 160000;

    char* ws = (char*)d_ws;
    __bf16* yp    = (__bf16*)ws;                // 4 partials x 20,480,000 B
    __bf16* ysum  = (__bf16*)(ws + 81920000);   // 20,480,000
    char*  W1p    = ws + 102400000;             //  2,097,152
    char*  W2p    = ws + 104497152;             //    524,288
    char*  Wgp    = ws + 105021440;             //    524,288
    __bf16* h1b   = (__bf16*)(ws + 105545728);  // 20,480,000
    float* alpha  = (float*)(ws + 126025728);   //     80,000
    int*   counts = (int*)(ws + 126105728);     //     80,000
    int*   offs   = (int*)(ws + 126185728);     //     80,004
    int*   cursor = (int*)(ws + 126265732);     //     80,000
    int*   eids   = (int*)(ws + 126345732);     //    640,000

    float* hout = (float*)d_out;                 // [20000][512] f32
    float* att  = hout + (size_t)M * H;          // [20000] f32

    // weights -> pre-tiled + pre-swizzled images (bf16)
    convw_pre_kernel<<<4096, 256, 0, stream>>>(W1, W1p, IN);
    convw_pre_kernel<<<1024, 256, 0, stream>>>(W2, W2p, H);
    convw_pre_kernel<<<1024, 256, 0, stream>>>(Wg, Wgp, H);

    // CSR build by dst
    hipMemsetAsync(counts, 0, M * 4, stream);
    count_kernel<<<(E + 255) / 256, 256, 0, stream>>>(ei + E, counts, E);
    scan_kernel<<<1, 1024, 0, stream>>>(counts, offs, M);
    hipMemsetAsync(cursor, 0, M * 4, stream);
    bucket_kernel<<<(E + 255) / 256, 256, 0, stream>>>(ei, ei + E, offs, cursor, eids, E);

    // y partials = x @ W1 (K-quarter split, barrier-free waves), then merge
    gemm1_kernel<<<dim3(313, 4), 512, 65536, stream>>>(x, W1p, yp, M);
    addy4_kernel<<<5000, 256, 0, stream>>>(yp, ysum);

    // h1 = bf16(relu(y_self + gather(y) + b1))   (one wave per node)
    gather_h1_kernel<<<5000, 256, 0, stream>>>(ysum, offs, eids, b1, h1b);

    // h = h1@W2+b2 -> d_out, fused alpha = rowsum(tanh(h@Wg+bg)*Wa)
    mlp23_kernel<<<625, 512, 0, stream>>>(h1b, W2p, b2, Wgp, bg, Wa, hout, alpha);

    // att = softmax(alpha)
    softmax_kernel<<<1, 1024, 0, stream>>>(alpha, att, M);
}